// Round 5
// baseline (255.396 us; speedup 1.0000x reference)
//
#include <hip/hip_runtime.h>
#include <math.h>

// Channelatt fused persistent kernel: x(32,256,56,56) f32 -> x * sigmoid(gate(n,c))
// 5 phases in one launch, separated by device-scope atomic grid barriers.

#define N_ 32
#define C_ 256
#define H_ 56
#define W_ 56
#define S_ 3136   // H_*W_
#define Q_ 784    // S_/4 (float4 units)
#define LN_EPS 1e-5f

#define NCH 16    // c-chunks in phase 1
#define CPC 16    // channels per chunk
#define GRID 512  // 16 chunks * 32 n  (2 blocks/CU -> co-resident)
#define NTHR 256

using f4 = __attribute__((ext_vector_type(4))) float;

__device__ __forceinline__ float wave_sum(float v) {
  #pragma unroll
  for (int o = 32; o > 0; o >>= 1) v += __shfl_xor(v, o);
  return v;
}
__device__ __forceinline__ float wave_max(float v) {
  #pragma unroll
  for (int o = 32; o > 0; o >>= 1) v = fmaxf(v, __shfl_xor(v, o));
  return v;
}
__device__ __forceinline__ float block_sum(float v, float* red) {
  int lane = threadIdx.x & 63, wid = threadIdx.x >> 6;
  float w = wave_sum(v);
  __syncthreads();
  if (lane == 0) red[wid] = w;
  __syncthreads();
  return red[0] + red[1] + red[2] + red[3];
}
__device__ __forceinline__ float dot4(f4 a, f4 b) {
  return a.x * b.x + a.y * b.y + a.z * b.z + a.w * b.w;
}
__device__ __forceinline__ float max4(f4 a) {
  return fmaxf(fmaxf(a.x, a.y), fmaxf(a.z, a.w));
}

// Device-scope grid barrier. bar zeroed by hipMemsetAsync before launch.
// All GRID blocks co-resident (launch_bounds 2 blocks/CU, grid=512=2*256CU).
__device__ __forceinline__ void grid_bar(unsigned* bar, unsigned target) {
  __syncthreads();
  if (threadIdx.x == 0) {
    __threadfence();   // release: make this block's writes visible device-wide
    __hip_atomic_fetch_add(bar, 1u, __ATOMIC_RELAXED, __HIP_MEMORY_SCOPE_AGENT);
    while (__hip_atomic_load(bar, __ATOMIC_RELAXED, __HIP_MEMORY_SCOPE_AGENT) < target)
      __builtin_amdgcn_s_sleep(2);
    __threadfence();   // acquire: don't let later reads see pre-barrier state
  }
  __syncthreads();
}

__global__ __launch_bounds__(NTHR, 2)
void k_fused(const float* __restrict__ x, const float* __restrict__ gc_w,
             const float* __restrict__ lc_w, const float* __restrict__ lc_b,
             const float* __restrict__ lcln_g, const float* __restrict__ lcln_b,
             const float* __restrict__ tw_w, const float* __restrict__ tw_b,
             const float* __restrict__ twln_g, const float* __restrict__ twln_b,
             const float* __restrict__ wdct, const float* __restrict__ wmax,
             float* __restrict__ out,
             unsigned* __restrict__ bar, float* __restrict__ lpart,
             float* __restrict__ attn, float* __restrict__ xg,
             float* __restrict__ xmax, float* __restrict__ xdct,
             float* __restrict__ gate) {
  const int tid = threadIdx.x;
  const int b = blockIdx.x;
  const int lane = tid & 63, wid = tid >> 6;

  // ---------- Phase 1: per (n, c-chunk): logit partials + final xmax/xdct ----------
  {
    __shared__ float bh[H_];
    __shared__ f4 bw4[14];
    __shared__ float gw[CPC];
    __shared__ float red2[2][4];
    int n = b >> 4, ch = b & 15, c0 = ch * CPC;
    // chunk spans one freq group (16 | 64): u,v constant per block
    int grp = c0 >> 6;
    int u = grp >> 1, vv = grp & 1;
    const float invs = 0.13363062f;   // 1/sqrt(56)
    const float sq2  = 1.41421356f;
    if (tid < H_) {
      float t = cosf((float)M_PI * u * (tid + 0.5f) / H_) * invs;
      bh[tid] = u ? t * sq2 : t;
    } else if (tid >= 64 && tid < 64 + 14) {
      int j = tid - 64;
      f4 t4;
      #pragma unroll
      for (int e = 0; e < 4; ++e) {
        float t = cosf((float)M_PI * vv * (4 * j + e + 0.5f) / W_) * invs;
        ((float*)&t4)[e] = vv ? t * sq2 : t;
      }
      bw4[j] = t4;
    }
    if (tid < CPC) gw[tid] = gc_w[c0 + tid];
    __syncthreads();
    const f4* xb = (const f4*)x + ((size_t)n * C_ + c0) * Q_;
    f4 A0 = {0,0,0,0}, A1 = {0,0,0,0}, A2 = {0,0,0,0}, A3 = {0,0,0,0};
    const int q0 = tid, q1 = tid + 256, q2 = tid + 512, q3 = tid + 768;
    for (int c = 0; c < CPC; ++c) {
      const f4* xp = xb + (size_t)c * Q_;
      float wgt = gw[c];
      f4 v0 = xp[q0], v1 = xp[q1], v2 = xp[q2];
      A0 += wgt * v0; A1 += wgt * v1; A2 += wgt * v2;
      float mx = fmaxf(fmaxf(max4(v0), max4(v1)), max4(v2));
      float d  = bh[q0 / 14] * dot4(v0, bw4[q0 % 14])
               + bh[q1 / 14] * dot4(v1, bw4[q1 % 14])
               + bh[q2 / 14] * dot4(v2, bw4[q2 % 14]);
      if (tid < 16) {
        f4 v3 = xp[q3];
        A3 += wgt * v3;
        mx = fmaxf(mx, max4(v3));
        d += bh[q3 / 14] * dot4(v3, bw4[q3 % 14]);
      }
      float ms = wave_max(mx), ds = wave_sum(d);
      __syncthreads();
      if (lane == 0) { red2[0][wid] = ms; red2[1][wid] = ds; }
      __syncthreads();
      if (tid == 0) {
        xmax[n * C_ + c0 + c] = fmaxf(fmaxf(red2[0][0], red2[0][1]),
                                      fmaxf(red2[0][2], red2[0][3]));
        xdct[n * C_ + c0 + c] = red2[1][0] + red2[1][1] + red2[1][2] + red2[1][3];
      }
    }
    f4* lp = (f4*)lpart + ((size_t)n * NCH + ch) * Q_;
    lp[q0] = A0; lp[q1] = A1; lp[q2] = A2;
    if (tid < 16) lp[q3] = A3;
  }
  grid_bar(bar, 1 * GRID);

  // ---------- Phase 2: softmax over s per n (blocks 0..31) ----------
  if (b < N_) {
    __shared__ float redm[4];
    int n = b;
    const f4* lp = (const f4*)lpart + (size_t)n * NCH * Q_;
    f4 v[4];
    float m = -INFINITY;
    #pragma unroll
    for (int k = 0; k < 3; ++k) {
      int q = tid + k * 256;
      f4 acc = {0,0,0,0};
      #pragma unroll
      for (int ch = 0; ch < NCH; ++ch) acc += lp[(size_t)ch * Q_ + q];
      v[k] = acc;
      m = fmaxf(m, max4(acc));
    }
    if (tid < 16) {
      f4 acc = {0,0,0,0};
      #pragma unroll
      for (int ch = 0; ch < NCH; ++ch) acc += lp[(size_t)ch * Q_ + 768 + tid];
      v[3] = acc;
      m = fmaxf(m, max4(acc));
    } else {
      v[3] = f4{-INFINITY, -INFINITY, -INFINITY, -INFINITY};
    }
    float wm = wave_max(m);
    if (lane == 0) redm[wid] = wm;
    __syncthreads();
    m = fmaxf(fmaxf(redm[0], redm[1]), fmaxf(redm[2], redm[3]));
    float z = 0.f;
    #pragma unroll
    for (int k = 0; k < 4; ++k) {
      v[k].x = expf(v[k].x - m); v[k].y = expf(v[k].y - m);
      v[k].z = expf(v[k].z - m); v[k].w = expf(v[k].w - m);
      z += v[k].x + v[k].y + v[k].z + v[k].w;
    }
    z = block_sum(z, redm);
    float inv = 1.f / z;
    f4* ap = (f4*)attn + (size_t)n * Q_;
    #pragma unroll
    for (int k = 0; k < 3; ++k) ap[tid + k * 256] = v[k] * inv;
    if (tid < 16) ap[768 + tid] = v[3] * inv;
  }
  grid_bar(bar, 2 * GRID);

  // ---------- Phase 3: x_g[n,c] = sum_s x*attn. 16 (n,c) tasks per block ----------
  {
    __shared__ float red1[4];
    #pragma unroll 1
    for (int i = 0; i < 16; ++i) {
      int t = b * 16 + i;
      int n = t >> 8, c = t & 255;
      const f4* xp = (const f4*)x + ((size_t)n * C_ + c) * Q_;
      const f4* ap = (const f4*)attn + (size_t)n * Q_;
      float g = 0.f;
      #pragma unroll
      for (int k = 0; k < 3; ++k) { int q = tid + k * 256; g += dot4(xp[q], ap[q]); }
      if (tid < 16) g += dot4(xp[768 + tid], ap[768 + tid]);
      g = block_sum(g, red1);
      if (tid == 0) xg[n * C_ + c] = g;
    }
  }
  grid_bar(bar, 3 * GRID);

  // ---------- Phase 4: gate math per n (blocks 0..31), thread = channel ----------
  if (b < N_) {
    __shared__ float xs[C_ + 2];
    __shared__ float att_s[C_];
    __shared__ float redg[4];
    int n = b, c = tid;
    float g  = xg[n * C_ + c];
    float sv = wmax[c] * xmax[n * C_ + c] + wdct[c] * xdct[n * C_ + c];
    xs[c + 1] = sv;
    if (c == 0) { xs[0] = 0.f; xs[C_ + 1] = 0.f; }
    __syncthreads();
    float xl = lc_w[0] * xs[c] + lc_w[1] * xs[c + 1] + lc_w[2] * xs[c + 2] + lc_b[0];
    float t = g + sv + xl;
    float mu  = block_sum(t, redg) * (1.f / C_);
    float dv  = t - mu;
    float var = block_sum(dv * dv, redg) * (1.f / C_);
    float att = dv * rsqrtf(var + LN_EPS) * lcln_g[c] + lcln_b[c];
    att_s[c] = att;
    __syncthreads();
    float a2 = tw_b[c];
    const f4* wrow = (const f4*)(tw_w + c * C_);
    const f4* arow = (const f4*)att_s;
    #pragma unroll 8
    for (int k = 0; k < C_ / 4; ++k) a2 += dot4(wrow[k], arow[k]);
    float mu2  = block_sum(a2, redg) * (1.f / C_);
    float d2   = a2 - mu2;
    float var2 = block_sum(d2 * d2, redg) * (1.f / C_);
    float z = d2 * rsqrtf(var2 + LN_EPS) * twln_g[c] + twln_b[c];
    gate[n * C_ + c] = 1.f / (1.f + expf(-z));
  }
  grid_bar(bar, 4 * GRID);

  // ---------- Phase 5: out = x * gate ----------
  {
    const f4* x4 = (const f4*)x;
    f4* o4 = (f4*)out;
    const int total = N_ * C_ * Q_;
    for (int i = b * NTHR + tid; i < total; i += GRID * NTHR) {
      float gv = gate[i / Q_];
      f4 v = x4[i];
      v *= gv;
      o4[i] = v;
    }
  }
}

extern "C" void kernel_launch(void* const* d_in, const int* in_sizes, int n_in,
                              void* d_out, int out_size, void* d_ws, size_t ws_size,
                              hipStream_t stream) {
  const float* x      = (const float*)d_in[0];
  const float* gc_w   = (const float*)d_in[1];
  // d_in[2] = gc_b: softmax shift-invariant, unused
  const float* lc_w   = (const float*)d_in[3];
  const float* lc_b   = (const float*)d_in[4];
  const float* lcln_g = (const float*)d_in[5];
  const float* lcln_b = (const float*)d_in[6];
  const float* tw_w   = (const float*)d_in[7];
  const float* tw_b   = (const float*)d_in[8];
  const float* twln_g = (const float*)d_in[9];
  const float* twln_b = (const float*)d_in[10];
  const float* wdct   = (const float*)d_in[11];
  const float* wmax   = (const float*)d_in[12];
  float* out = (float*)d_out;

  float* ws = (float*)d_ws;
  unsigned* bar = (unsigned*)ws;                      // [64] floats reserved
  float* lpart  = ws + 64;                            // NCH*N*S
  float* attn   = lpart + (size_t)NCH * N_ * S_;      // N*S
  float* xg     = attn + (size_t)N_ * S_;             // N*C
  float* xmax_  = xg + N_ * C_;
  float* xdct_  = xmax_ + N_ * C_;
  float* gate   = xdct_ + N_ * C_;

  (void)hipMemsetAsync(bar, 0, 256, stream);
  hipLaunchKernelGGL(k_fused, dim3(GRID), dim3(NTHR), 0, stream,
                     x, gc_w, lc_w, lc_b, lcln_g, lcln_b,
                     tw_b ? tw_w : tw_w, tw_b, twln_g, twln_b, wdct, wmax,
                     out, bar, lpart, attn, xg, xmax_, xdct_, gate);
}

// Round 6
// 109.227 us; speedup vs baseline: 2.3382x; 2.3382x over previous
//
#include <hip/hip_runtime.h>
#include <math.h>

// Channelatt: x(32,256,56,56) f32 -> x * sigmoid(gate(n,c))
// 5-kernel pipeline; pass structure is minimal: logits+max+dct(read x) ->
// softmax -> xg(read x) -> gate -> scale(read x, write out). L3 absorbs re-reads.

#define N_ 32
#define C_ 256
#define H_ 56
#define W_ 56
#define S_ 3136   // H_*W_
#define Q_ 784    // S_/4 (float4 units)
#define LN_EPS 1e-5f

#define NCH 16    // c-chunks in pass 1
#define CPC 16    // channels per chunk (NCH*CPC == C_)

using f4 = __attribute__((ext_vector_type(4))) float;

__device__ __forceinline__ float wave_sum(float v) {
  #pragma unroll
  for (int o = 32; o > 0; o >>= 1) v += __shfl_xor(v, o);
  return v;
}
__device__ __forceinline__ float wave_max(float v) {
  #pragma unroll
  for (int o = 32; o > 0; o >>= 1) v = fmaxf(v, __shfl_xor(v, o));
  return v;
}
__device__ __forceinline__ float block_sum(float v, float* red) {
  int lane = threadIdx.x & 63, wid = threadIdx.x >> 6;
  float w = wave_sum(v);
  __syncthreads();
  if (lane == 0) red[wid] = w;
  __syncthreads();
  return red[0] + red[1] + red[2] + red[3];
}
__device__ __forceinline__ float dot4(f4 a, f4 b) {
  return a.x * b.x + a.y * b.y + a.z * b.z + a.w * b.w;
}
__device__ __forceinline__ float max4(f4 a) {
  return fmaxf(fmaxf(a.x, a.y), fmaxf(a.z, a.w));
}

// K1: one cold pass over x: logit partials + per-channel xmax/xdct.
// Per-channel max/dct accumulate in REGISTERS (mx[16], dc[16], unrolled
// c loop) -> no inner-loop reductions/barriers.
__global__ __launch_bounds__(256)
void k1_pool(const float* __restrict__ x, const float* __restrict__ gc_w,
             float* __restrict__ lpart, float* __restrict__ xmax,
             float* __restrict__ xdct) {
  int ch = blockIdx.x, n = blockIdx.y, tid = threadIdx.x;
  int c0 = ch * CPC;
  __shared__ float gw[CPC];
  __shared__ float bh[H_];
  __shared__ f4 bw4[14];
  __shared__ float redm[4][CPC], redd[4][CPC];
  int grp = c0 >> 6;                 // freq group: (u,v) in {0,1}^2
  int u = grp >> 1, vv = grp & 1;
  const float invs = 0.13363062f;    // 1/sqrt(56)
  const float sq2  = 1.41421356f;
  if (tid < H_) {
    float t = cosf((float)M_PI * u * (tid + 0.5f) / H_) * invs;
    bh[tid] = u ? t * sq2 : t;
  } else if (tid >= 64 && tid < 64 + 14) {
    int j = tid - 64;
    f4 t4;
    #pragma unroll
    for (int e = 0; e < 4; ++e) {
      float t = cosf((float)M_PI * vv * (4 * j + e + 0.5f) / W_) * invs;
      ((float*)&t4)[e] = vv ? t * sq2 : t;
    }
    bw4[j] = t4;
  }
  if (tid < CPC) gw[tid] = gc_w[c0 + tid];
  __syncthreads();

  const int q0 = tid, q1 = tid + 256, q2 = tid + 512, q3 = tid + 768;
  const bool has3 = (tid < 16);
  float bh0 = bh[q0 / 14], bh1 = bh[q1 / 14], bh2 = bh[q2 / 14];
  f4 bw0 = bw4[q0 % 14], bw1 = bw4[q1 % 14], bw2 = bw4[q2 % 14];
  float bh3 = 0.f; f4 bw3 = {0,0,0,0};
  if (has3) { bh3 = bh[q3 / 14]; bw3 = bw4[q3 % 14]; }

  const f4* xb = (const f4*)x + ((size_t)n * C_ + c0) * Q_;
  f4 A0 = {0,0,0,0}, A1 = {0,0,0,0}, A2 = {0,0,0,0}, A3 = {0,0,0,0};
  float mx[CPC], dc[CPC];
  #pragma unroll
  for (int c = 0; c < CPC; ++c) {
    const f4* xp = xb + (size_t)c * Q_;
    float wgt = gw[c];
    f4 v0 = xp[q0], v1 = xp[q1], v2 = xp[q2];
    A0 += wgt * v0; A1 += wgt * v1; A2 += wgt * v2;
    float m = fmaxf(fmaxf(max4(v0), max4(v1)), max4(v2));
    float d = bh0 * dot4(v0, bw0) + bh1 * dot4(v1, bw1) + bh2 * dot4(v2, bw2);
    if (has3) {
      f4 v3 = xp[q3];
      A3 += wgt * v3;
      m = fmaxf(m, max4(v3));
      d += bh3 * dot4(v3, bw3);
    }
    mx[c] = m; dc[c] = d;
  }
  f4* lp = (f4*)lpart + ((size_t)n * NCH + ch) * Q_;
  lp[q0] = A0; lp[q1] = A1; lp[q2] = A2;
  if (has3) lp[q3] = A3;

  int lane = tid & 63, wid = tid >> 6;
  #pragma unroll
  for (int c = 0; c < CPC; ++c) {
    float m = wave_max(mx[c]);
    float d = wave_sum(dc[c]);
    if (lane == 0) { redm[wid][c] = m; redd[wid][c] = d; }
  }
  __syncthreads();
  if (tid < CPC) {
    float m = fmaxf(fmaxf(redm[0][tid], redm[1][tid]),
                    fmaxf(redm[2][tid], redm[3][tid]));
    float d = redd[0][tid] + redd[1][tid] + redd[2][tid] + redd[3][tid];
    xmax[n * C_ + c0 + tid] = m;
    xdct[n * C_ + c0 + tid] = d;
  }
}

// K2: fold 16 partials -> softmax over s per n. One block per n, float4.
__global__ void k_softmax(const float* __restrict__ lpart, float* __restrict__ attn) {
  int n = blockIdx.x, tid = threadIdx.x;
  __shared__ float red[4];
  const f4* lp = (const f4*)lpart + (size_t)n * NCH * Q_;
  f4 v[4];
  float m = -INFINITY;
  #pragma unroll
  for (int k = 0; k < 3; ++k) {
    int q = tid + k * 256;
    f4 acc = {0,0,0,0};
    #pragma unroll
    for (int ch = 0; ch < NCH; ++ch) acc += lp[(size_t)ch * Q_ + q];
    v[k] = acc;
    m = fmaxf(m, max4(acc));
  }
  if (tid < 16) {
    f4 acc = {0,0,0,0};
    #pragma unroll
    for (int ch = 0; ch < NCH; ++ch) acc += lp[(size_t)ch * Q_ + 768 + tid];
    v[3] = acc;
    m = fmaxf(m, max4(acc));
  } else {
    v[3] = f4{-INFINITY, -INFINITY, -INFINITY, -INFINITY};
  }
  float wm = wave_max(m);
  int lane = tid & 63, wid = tid >> 6;
  if (lane == 0) red[wid] = wm;
  __syncthreads();
  m = fmaxf(fmaxf(red[0], red[1]), fmaxf(red[2], red[3]));
  float z = 0.f;
  #pragma unroll
  for (int k = 0; k < 4; ++k) {
    v[k].x = expf(v[k].x - m); v[k].y = expf(v[k].y - m);
    v[k].z = expf(v[k].z - m); v[k].w = expf(v[k].w - m);
    z += v[k].x + v[k].y + v[k].z + v[k].w;   // exp(-inf)=0 for tail lanes
  }
  z = block_sum(z, red);
  float inv = 1.f / z;
  f4* ap = (f4*)attn + (size_t)n * Q_;
  #pragma unroll
  for (int k = 0; k < 3; ++k) ap[tid + k * 256] = v[k] * inv;
  if (tid < 16) ap[768 + tid] = v[3] * inv;
}

// K3: pure dot: xg[n,c] = sum_s x*attn. Block per (c,n).
__global__ void k3_xg(const float* __restrict__ x, const float* __restrict__ attn,
                      float* __restrict__ xg) {
  int c = blockIdx.x, n = blockIdx.y, tid = threadIdx.x;
  __shared__ float red[4];
  const f4* xp = (const f4*)x + ((size_t)n * C_ + c) * Q_;
  const f4* ap = (const f4*)attn + (size_t)n * Q_;
  float g = 0.f;
  #pragma unroll
  for (int k = 0; k < 3; ++k) { int q = tid + k * 256; g += dot4(xp[q], ap[q]); }
  if (tid < 16) g += dot4(xp[768 + tid], ap[768 + tid]);
  g = block_sum(g, red);
  if (tid == 0) xg[n * C_ + c] = g;
}

// K4: per-(n,c) gate math. One block per n, thread = channel.
__global__ void k_gate(const float* __restrict__ xg, const float* __restrict__ xmax,
                       const float* __restrict__ xdct,
                       const float* __restrict__ lc_w, const float* __restrict__ lc_b,
                       const float* __restrict__ lcln_g, const float* __restrict__ lcln_b,
                       const float* __restrict__ tw_w, const float* __restrict__ tw_b,
                       const float* __restrict__ twln_g, const float* __restrict__ twln_b,
                       const float* __restrict__ wdct, const float* __restrict__ wmax,
                       float* __restrict__ gate) {
  int n = blockIdx.x, c = threadIdx.x;
  __shared__ float xs[C_ + 2];
  __shared__ float att_s[C_];
  __shared__ float red[4];
  float g  = xg[n * C_ + c];
  float sv = wmax[c] * xmax[n * C_ + c] + wdct[c] * xdct[n * C_ + c];
  xs[c + 1] = sv;
  if (c == 0) { xs[0] = 0.f; xs[C_ + 1] = 0.f; }
  __syncthreads();
  float xl = lc_w[0] * xs[c] + lc_w[1] * xs[c + 1] + lc_w[2] * xs[c + 2] + lc_b[0];
  float t = g + sv + xl;
  float mu  = block_sum(t, red) * (1.f / C_);
  float dv  = t - mu;
  float var = block_sum(dv * dv, red) * (1.f / C_);
  float att = dv * rsqrtf(var + LN_EPS) * lcln_g[c] + lcln_b[c];
  att_s[c] = att;
  __syncthreads();
  float a2 = tw_b[c];
  const f4* wrow = (const f4*)(tw_w + c * C_);
  const f4* arow = (const f4*)att_s;
  #pragma unroll 8
  for (int k = 0; k < C_ / 4; ++k) a2 += dot4(wrow[k], arow[k]);
  float mu2  = block_sum(a2, red) * (1.f / C_);
  float d2   = a2 - mu2;
  float var2 = block_sum(d2 * d2, red) * (1.f / C_);
  float z = d2 * rsqrtf(var2 + LN_EPS) * twln_g[c] + twln_b[c];
  gate[n * C_ + c] = 1.f / (1.f + expf(-z));
}

// K5: out = x * gate[n,c], float4 grid-stride.
__global__ void k_scale(const float* __restrict__ x, const float* __restrict__ gate,
                        float* __restrict__ out) {
  const f4* x4 = (const f4*)x;
  f4* o4 = (f4*)out;
  const int total = N_ * C_ * Q_;
  for (int i = blockIdx.x * blockDim.x + threadIdx.x; i < total;
       i += gridDim.x * blockDim.x) {
    int nc = i / Q_;
    float gv = gate[nc];
    f4 v = x4[i];
    v *= gv;
    o4[i] = v;
  }
}

extern "C" void kernel_launch(void* const* d_in, const int* in_sizes, int n_in,
                              void* d_out, int out_size, void* d_ws, size_t ws_size,
                              hipStream_t stream) {
  const float* x      = (const float*)d_in[0];
  const float* gc_w   = (const float*)d_in[1];
  // d_in[2] = gc_b: softmax shift-invariant, unused
  const float* lc_w   = (const float*)d_in[3];
  const float* lc_b   = (const float*)d_in[4];
  const float* lcln_g = (const float*)d_in[5];
  const float* lcln_b = (const float*)d_in[6];
  const float* tw_w   = (const float*)d_in[7];
  const float* tw_b   = (const float*)d_in[8];
  const float* twln_g = (const float*)d_in[9];
  const float* twln_b = (const float*)d_in[10];
  const float* wdct   = (const float*)d_in[11];
  const float* wmax   = (const float*)d_in[12];
  float* out = (float*)d_out;

  float* ws    = (float*)d_ws;
  float* lpart = ws;                                   // NCH*N*S
  float* attn  = lpart + (size_t)NCH * N_ * S_;        // N*S
  float* xg    = attn + (size_t)N_ * S_;               // N*C
  float* xmax_ = xg + N_ * C_;
  float* xdct_ = xmax_ + N_ * C_;
  float* gate  = xdct_ + N_ * C_;

  hipLaunchKernelGGL(k1_pool, dim3(NCH, N_), dim3(256), 0, stream,
                     x, gc_w, lpart, xmax_, xdct_);
  hipLaunchKernelGGL(k_softmax, dim3(N_), dim3(256), 0, stream, lpart, attn);
  hipLaunchKernelGGL(k3_xg, dim3(C_, N_), dim3(256), 0, stream, x, attn, xg);
  hipLaunchKernelGGL(k_gate, dim3(N_), dim3(256), 0, stream,
                     xg, xmax_, xdct_, lc_w, lc_b, lcln_g, lcln_b,
                     tw_w, tw_b, twln_g, twln_b, wdct, wmax, gate);
  hipLaunchKernelGGL(k_scale, dim3(2048), dim3(256), 0, stream, x, gate, out);
}

// Round 7
// 88.119 us; speedup vs baseline: 2.8983x; 1.2395x over previous
//
#include <hip/hip_runtime.h>
#include <math.h>

// Channelatt: x(32,256,56,56) f32 -> x * sigmoid(gate(n,c))
// Pipeline: k1 logits (x cold read, 512 blocks) -> k2 softmax ->
// k3 stats xg+max+dct (x warm read, 8192 blocks) -> k4 gate -> k5 scale.
// Lesson R6: keep pass-1 bodies lean (latency-bound at 2 blocks/CU);
// heavy per-channel reductions belong in the 8192-block pass.

#define N_ 32
#define C_ 256
#define H_ 56
#define W_ 56
#define S_ 3136   // H_*W_
#define Q_ 784    // S_/4 (float4 units)
#define LN_EPS 1e-5f

#define NCH 16    // c-chunks in pass 1
#define CPC 16    // channels per chunk (NCH*CPC == C_)

using f4 = __attribute__((ext_vector_type(4))) float;

__device__ __forceinline__ float wave_sum(float v) {
  #pragma unroll
  for (int o = 32; o > 0; o >>= 1) v += __shfl_xor(v, o);
  return v;
}
__device__ __forceinline__ float wave_max(float v) {
  #pragma unroll
  for (int o = 32; o > 0; o >>= 1) v = fmaxf(v, __shfl_xor(v, o));
  return v;
}
__device__ __forceinline__ float block_sum(float v, float* red) {
  int lane = threadIdx.x & 63, wid = threadIdx.x >> 6;
  float w = wave_sum(v);
  __syncthreads();
  if (lane == 0) red[wid] = w;
  __syncthreads();
  return red[0] + red[1] + red[2] + red[3];
}
__device__ __forceinline__ float dot4(f4 a, f4 b) {
  return a.x * b.x + a.y * b.y + a.z * b.z + a.w * b.w;
}
__device__ __forceinline__ float max4(f4 a) {
  return fmaxf(fmaxf(a.x, a.y), fmaxf(a.z, a.w));
}

// K1: partial logits only — lean body, pure FMA per load.
__global__ __launch_bounds__(256)
void k_logits(const float* __restrict__ x, const float* __restrict__ gc_w,
              float* __restrict__ lpart) {
  int ch = blockIdx.x, n = blockIdx.y, tid = threadIdx.x;
  int c0 = ch * CPC;
  __shared__ float gw[CPC];
  if (tid < CPC) gw[tid] = gc_w[c0 + tid];
  __syncthreads();
  const f4* xb = (const f4*)x + ((size_t)n * C_ + c0) * Q_;
  f4 A0 = {0,0,0,0}, A1 = {0,0,0,0}, A2 = {0,0,0,0}, A3 = {0,0,0,0};
  const int q0 = tid, q1 = tid + 256, q2 = tid + 512, q3 = tid + 768;
  const bool has3 = (tid < 16);
  #pragma unroll 8
  for (int c = 0; c < CPC; ++c) {
    const f4* xp = xb + (size_t)c * Q_;
    float wgt = gw[c];
    A0 += wgt * xp[q0];
    A1 += wgt * xp[q1];
    A2 += wgt * xp[q2];
    if (has3) A3 += wgt * xp[q3];
  }
  f4* lp = (f4*)lpart + ((size_t)n * NCH + ch) * Q_;
  lp[q0] = A0; lp[q1] = A1; lp[q2] = A2;
  if (has3) lp[q3] = A3;
}

// K2: fold 16 partials -> softmax over s per n. One block per n, float4.
__global__ void k_softmax(const float* __restrict__ lpart, float* __restrict__ attn) {
  int n = blockIdx.x, tid = threadIdx.x;
  __shared__ float red[4];
  const f4* lp = (const f4*)lpart + (size_t)n * NCH * Q_;
  f4 v[4];
  float m = -INFINITY;
  #pragma unroll
  for (int k = 0; k < 3; ++k) {
    int q = tid + k * 256;
    f4 acc = {0,0,0,0};
    #pragma unroll
    for (int ch = 0; ch < NCH; ++ch) acc += lp[(size_t)ch * Q_ + q];
    v[k] = acc;
    m = fmaxf(m, max4(acc));
  }
  if (tid < 16) {
    f4 acc = {0,0,0,0};
    #pragma unroll
    for (int ch = 0; ch < NCH; ++ch) acc += lp[(size_t)ch * Q_ + 768 + tid];
    v[3] = acc;
    m = fmaxf(m, max4(acc));
  } else {
    v[3] = f4{-INFINITY, -INFINITY, -INFINITY, -INFINITY};
  }
  float wm = wave_max(m);
  int lane = tid & 63, wid = tid >> 6;
  if (lane == 0) red[wid] = wm;
  __syncthreads();
  m = fmaxf(fmaxf(red[0], red[1]), fmaxf(red[2], red[3]));
  float z = 0.f;
  #pragma unroll
  for (int k = 0; k < 4; ++k) {
    v[k].x = expf(v[k].x - m); v[k].y = expf(v[k].y - m);
    v[k].z = expf(v[k].z - m); v[k].w = expf(v[k].w - m);
    z += v[k].x + v[k].y + v[k].z + v[k].w;   // exp(-inf)=0 for tail lanes
  }
  z = block_sum(z, red);
  float inv = 1.f / z;
  f4* ap = (f4*)attn + (size_t)n * Q_;
  #pragma unroll
  for (int k = 0; k < 3; ++k) ap[tid + k * 256] = v[k] * inv;
  if (tid < 16) ap[768 + tid] = v[3] * inv;
}

// K3: per (n,c): x_g, x_max, x_dct in one warm x pass. Block per (c,n) = 8192.
__global__ void k_stats(const float* __restrict__ x, const float* __restrict__ attn,
                        float* __restrict__ xg, float* __restrict__ xmax,
                        float* __restrict__ xdct) {
  int c = blockIdx.x, n = blockIdx.y, tid = threadIdx.x;
  __shared__ float bh[H_];
  __shared__ f4 bw4[14];
  __shared__ float red[3][4];
  int grp = c >> 6;
  int u = grp >> 1, vv = grp & 1;
  const float invs = 0.13363062f;   // 1/sqrt(56)
  const float sq2  = 1.41421356f;
  if (tid < H_) {
    float b = cosf((float)M_PI * u * (tid + 0.5f) / H_) * invs;
    bh[tid] = u ? b * sq2 : b;
  } else if (tid >= 64 && tid < 64 + 14) {
    int j = tid - 64;
    f4 b;
    #pragma unroll
    for (int e = 0; e < 4; ++e) {
      float t = cosf((float)M_PI * vv * (4 * j + e + 0.5f) / W_) * invs;
      ((float*)&b)[e] = vv ? t * sq2 : t;
    }
    bw4[j] = b;
  }
  __syncthreads();
  const f4* xp = (const f4*)(x + ((size_t)n * C_ + c) * S_);
  const f4* ap = (const f4*)(attn + (size_t)n * S_);
  float g = 0.f, d = 0.f, mx = -INFINITY;
  #pragma unroll
  for (int k = 0; k < 3; ++k) {
    int q = tid + k * 256;
    f4 xv = xp[q], av = ap[q];
    g += dot4(xv, av);
    mx = fmaxf(max4(xv), mx);
    int h = q / 14;
    d += bh[h] * dot4(xv, bw4[q - h * 14]);
  }
  if (tid < 16) {
    int q = 768 + tid;
    f4 xv = xp[q], av = ap[q];
    g += dot4(xv, av);
    mx = fmaxf(max4(xv), mx);
    int h = q / 14;
    d += bh[h] * dot4(xv, bw4[q - h * 14]);
  }
  float gs = wave_sum(g), ms = wave_max(mx), ds = wave_sum(d);
  int lane = tid & 63, wid = tid >> 6;
  if (lane == 0) { red[0][wid] = gs; red[1][wid] = ms; red[2][wid] = ds; }
  __syncthreads();
  if (tid == 0) {
    xg[n * C_ + c]   = red[0][0] + red[0][1] + red[0][2] + red[0][3];
    xmax[n * C_ + c] = fmaxf(fmaxf(red[1][0], red[1][1]), fmaxf(red[1][2], red[1][3]));
    xdct[n * C_ + c] = red[2][0] + red[2][1] + red[2][2] + red[2][3];
  }
}

// K4: per-(n,c) gate math. One block per n, thread = channel.
__global__ void k_gate(const float* __restrict__ xg, const float* __restrict__ xmax,
                       const float* __restrict__ xdct,
                       const float* __restrict__ lc_w, const float* __restrict__ lc_b,
                       const float* __restrict__ lcln_g, const float* __restrict__ lcln_b,
                       const float* __restrict__ tw_w, const float* __restrict__ tw_b,
                       const float* __restrict__ twln_g, const float* __restrict__ twln_b,
                       const float* __restrict__ wdct, const float* __restrict__ wmax,
                       float* __restrict__ gate) {
  int n = blockIdx.x, c = threadIdx.x;
  __shared__ float xs[C_ + 2];
  __shared__ float att_s[C_];
  __shared__ float red[4];
  float g  = xg[n * C_ + c];
  float sv = wmax[c] * xmax[n * C_ + c] + wdct[c] * xdct[n * C_ + c];
  xs[c + 1] = sv;
  if (c == 0) { xs[0] = 0.f; xs[C_ + 1] = 0.f; }
  __syncthreads();
  float xl = lc_w[0] * xs[c] + lc_w[1] * xs[c + 1] + lc_w[2] * xs[c + 2] + lc_b[0];
  float t = g + sv + xl;
  float mu  = block_sum(t, red) * (1.f / C_);
  float dv  = t - mu;
  float var = block_sum(dv * dv, red) * (1.f / C_);
  float att = dv * rsqrtf(var + LN_EPS) * lcln_g[c] + lcln_b[c];
  att_s[c] = att;
  __syncthreads();
  float a2 = tw_b[c];
  const f4* wrow = (const f4*)(tw_w + c * C_);
  const f4* arow = (const f4*)att_s;
  #pragma unroll 8
  for (int k = 0; k < C_ / 4; ++k) a2 += dot4(wrow[k], arow[k]);
  float mu2  = block_sum(a2, red) * (1.f / C_);
  float d2   = a2 - mu2;
  float var2 = block_sum(d2 * d2, red) * (1.f / C_);
  float z = d2 * rsqrtf(var2 + LN_EPS) * twln_g[c] + twln_b[c];
  gate[n * C_ + c] = 1.f / (1.f + expf(-z));
}

// K5: out = x * gate[n,c], float4 grid-stride.
__global__ void k_scale(const float* __restrict__ x, const float* __restrict__ gate,
                        float* __restrict__ out) {
  const f4* x4 = (const f4*)x;
  f4* o4 = (f4*)out;
  const int total = N_ * C_ * Q_;
  for (int i = blockIdx.x * blockDim.x + threadIdx.x; i < total;
       i += gridDim.x * blockDim.x) {
    int nc = i / Q_;
    float gv = gate[nc];
    f4 v = x4[i];
    v *= gv;
    o4[i] = v;
  }
}

extern "C" void kernel_launch(void* const* d_in, const int* in_sizes, int n_in,
                              void* d_out, int out_size, void* d_ws, size_t ws_size,
                              hipStream_t stream) {
  const float* x      = (const float*)d_in[0];
  const float* gc_w   = (const float*)d_in[1];
  // d_in[2] = gc_b: softmax shift-invariant, unused
  const float* lc_w   = (const float*)d_in[3];
  const float* lc_b   = (const float*)d_in[4];
  const float* lcln_g = (const float*)d_in[5];
  const float* lcln_b = (const float*)d_in[6];
  const float* tw_w   = (const float*)d_in[7];
  const float* tw_b   = (const float*)d_in[8];
  const float* twln_g = (const float*)d_in[9];
  const float* twln_b = (const float*)d_in[10];
  const float* wdct   = (const float*)d_in[11];
  const float* wmax   = (const float*)d_in[12];
  float* out = (float*)d_out;

  float* ws    = (float*)d_ws;
  float* lpart = ws;                                   // NCH*N*S
  float* attn  = lpart + (size_t)NCH * N_ * S_;        // N*S
  float* xg    = attn + (size_t)N_ * S_;               // N*C
  float* xmax_ = xg + N_ * C_;
  float* xdct_ = xmax_ + N_ * C_;
  float* gate  = xdct_ + N_ * C_;

  hipLaunchKernelGGL(k_logits, dim3(NCH, N_), dim3(256), 0, stream, x, gc_w, lpart);
  hipLaunchKernelGGL(k_softmax, dim3(N_), dim3(256), 0, stream, lpart, attn);
  hipLaunchKernelGGL(k_stats, dim3(C_, N_), dim3(256), 0, stream, x, attn, xg, xmax_, xdct_);
  hipLaunchKernelGGL(k_gate, dim3(N_), dim3(256), 0, stream,
                     xg, xmax_, xdct_, lc_w, lc_b, lcln_g, lcln_b,
                     tw_w, tw_b, twln_g, twln_b, wdct, wmax, gate);
  hipLaunchKernelGGL(k_scale, dim3(2048), dim3(256), 0, stream, x, gate, out);
}

// Round 8
// 87.718 us; speedup vs baseline: 2.9116x; 1.0046x over previous
//
#include <hip/hip_runtime.h>
#include <math.h>

// Channelatt: x(32,256,56,56) f32 -> x * sigmoid(gate(n,c))
// Pipeline: k1 logits (x cold read, 2048 blocks) -> k2 softmax ->
// k3 stats xg+max+dct (x warm read, 8192 blocks) -> k4 gate -> k5 scale.
// Lesson R6/R7: latency-bound reduction passes need >=2000 blocks (8/CU);
// a 512-block grid idles at ~10% occupancy and reads HBM at 2 TB/s.

#define N_ 32
#define C_ 256
#define H_ 56
#define W_ 56
#define S_ 3136   // H_*W_
#define Q_ 784    // S_/4 (float4 units)
#define LN_EPS 1e-5f

#define NCH 16    // c-chunks in pass 1
#define CPC 16    // channels per chunk (NCH*CPC == C_)
#define SQ  4     // s-chunks in pass 1
#define QCH 196   // f4 per s-chunk (Q_/SQ)

using f4 = __attribute__((ext_vector_type(4))) float;

__device__ __forceinline__ float wave_sum(float v) {
  #pragma unroll
  for (int o = 32; o > 0; o >>= 1) v += __shfl_xor(v, o);
  return v;
}
__device__ __forceinline__ float wave_max(float v) {
  #pragma unroll
  for (int o = 32; o > 0; o >>= 1) v = fmaxf(v, __shfl_xor(v, o));
  return v;
}
__device__ __forceinline__ float block_sum(float v, float* red) {
  int lane = threadIdx.x & 63, wid = threadIdx.x >> 6;
  float w = wave_sum(v);
  __syncthreads();
  if (lane == 0) red[wid] = w;
  __syncthreads();
  return red[0] + red[1] + red[2] + red[3];
}
__device__ __forceinline__ float dot4(f4 a, f4 b) {
  return a.x * b.x + a.y * b.y + a.z * b.z + a.w * b.w;
}
__device__ __forceinline__ float max4(f4 a) {
  return fmaxf(fmaxf(a.x, a.y), fmaxf(a.z, a.w));
}

// K1: partial logits. Block = (c-chunk, n, s-chunk) = 16*32*4 = 2048 blocks.
// Active thread owns one f4 position, loops 16 channels (independent loads).
__global__ __launch_bounds__(256)
void k_logits(const float* __restrict__ x, const float* __restrict__ gc_w,
              float* __restrict__ lpart) {
  int ch = blockIdx.x, n = blockIdx.y, sq = blockIdx.z;
  int tid = threadIdx.x;
  int c0 = ch * CPC;
  __shared__ float gw[CPC];
  if (tid < CPC) gw[tid] = gc_w[c0 + tid];
  __syncthreads();
  if (tid >= QCH) return;
  int q = sq * QCH + tid;
  const f4* xb = (const f4*)x + ((size_t)n * C_ + c0) * Q_ + q;
  f4 A = {0,0,0,0};
  #pragma unroll
  for (int c = 0; c < CPC; ++c) A += gw[c] * xb[(size_t)c * Q_];
  ((f4*)lpart)[((size_t)n * NCH + ch) * Q_ + q] = A;
}

// K2: fold 16 partials -> softmax over s per n. One block per n, float4.
__global__ void k_softmax(const float* __restrict__ lpart, float* __restrict__ attn) {
  int n = blockIdx.x, tid = threadIdx.x;
  __shared__ float red[4];
  const f4* lp = (const f4*)lpart + (size_t)n * NCH * Q_;
  f4 v[4];
  float m = -INFINITY;
  #pragma unroll
  for (int k = 0; k < 3; ++k) {
    int q = tid + k * 256;
    f4 acc = {0,0,0,0};
    #pragma unroll
    for (int ch = 0; ch < NCH; ++ch) acc += lp[(size_t)ch * Q_ + q];
    v[k] = acc;
    m = fmaxf(m, max4(acc));
  }
  if (tid < 16) {
    f4 acc = {0,0,0,0};
    #pragma unroll
    for (int ch = 0; ch < NCH; ++ch) acc += lp[(size_t)ch * Q_ + 768 + tid];
    v[3] = acc;
    m = fmaxf(m, max4(acc));
  } else {
    v[3] = f4{-INFINITY, -INFINITY, -INFINITY, -INFINITY};
  }
  float wm = wave_max(m);
  int lane = tid & 63, wid = tid >> 6;
  if (lane == 0) red[wid] = wm;
  __syncthreads();
  m = fmaxf(fmaxf(red[0], red[1]), fmaxf(red[2], red[3]));
  float z = 0.f;
  #pragma unroll
  for (int k = 0; k < 4; ++k) {
    v[k].x = expf(v[k].x - m); v[k].y = expf(v[k].y - m);
    v[k].z = expf(v[k].z - m); v[k].w = expf(v[k].w - m);
    z += v[k].x + v[k].y + v[k].z + v[k].w;   // exp(-inf)=0 for tail lanes
  }
  z = block_sum(z, red);
  float inv = 1.f / z;
  f4* ap = (f4*)attn + (size_t)n * Q_;
  #pragma unroll
  for (int k = 0; k < 3; ++k) ap[tid + k * 256] = v[k] * inv;
  if (tid < 16) ap[768 + tid] = v[3] * inv;
}

// K3: per (n,c): x_g, x_max, x_dct in one warm x pass. Block per (c,n) = 8192.
__global__ void k_stats(const float* __restrict__ x, const float* __restrict__ attn,
                        float* __restrict__ xg, float* __restrict__ xmax,
                        float* __restrict__ xdct) {
  int c = blockIdx.x, n = blockIdx.y, tid = threadIdx.x;
  __shared__ float bh[H_];
  __shared__ f4 bw4[14];
  __shared__ float red[3][4];
  int grp = c >> 6;
  int u = grp >> 1, vv = grp & 1;
  const float invs = 0.13363062f;   // 1/sqrt(56)
  const float sq2  = 1.41421356f;
  if (tid < H_) {
    float b = cosf((float)M_PI * u * (tid + 0.5f) / H_) * invs;
    bh[tid] = u ? b * sq2 : b;
  } else if (tid >= 64 && tid < 64 + 14) {
    int j = tid - 64;
    f4 b;
    #pragma unroll
    for (int e = 0; e < 4; ++e) {
      float t = cosf((float)M_PI * vv * (4 * j + e + 0.5f) / W_) * invs;
      ((float*)&b)[e] = vv ? t * sq2 : t;
    }
    bw4[j] = b;
  }
  __syncthreads();
  const f4* xp = (const f4*)(x + ((size_t)n * C_ + c) * S_);
  const f4* ap = (const f4*)(attn + (size_t)n * S_);
  float g = 0.f, d = 0.f, mx = -INFINITY;
  #pragma unroll
  for (int k = 0; k < 3; ++k) {
    int q = tid + k * 256;
    f4 xv = xp[q], av = ap[q];
    g += dot4(xv, av);
    mx = fmaxf(max4(xv), mx);
    int h = q / 14;
    d += bh[h] * dot4(xv, bw4[q - h * 14]);
  }
  if (tid < 16) {
    int q = 768 + tid;
    f4 xv = xp[q], av = ap[q];
    g += dot4(xv, av);
    mx = fmaxf(max4(xv), mx);
    int h = q / 14;
    d += bh[h] * dot4(xv, bw4[q - h * 14]);
  }
  float gs = wave_sum(g), ms = wave_max(mx), ds = wave_sum(d);
  int lane = tid & 63, wid = tid >> 6;
  if (lane == 0) { red[0][wid] = gs; red[1][wid] = ms; red[2][wid] = ds; }
  __syncthreads();
  if (tid == 0) {
    xg[n * C_ + c]   = red[0][0] + red[0][1] + red[0][2] + red[0][3];
    xmax[n * C_ + c] = fmaxf(fmaxf(red[1][0], red[1][1]), fmaxf(red[1][2], red[1][3]));
    xdct[n * C_ + c] = red[2][0] + red[2][1] + red[2][2] + red[2][3];
  }
}

// K4: per-(n,c) gate math. One block per n, thread = channel.
__global__ void k_gate(const float* __restrict__ xg, const float* __restrict__ xmax,
                       const float* __restrict__ xdct,
                       const float* __restrict__ lc_w, const float* __restrict__ lc_b,
                       const float* __restrict__ lcln_g, const float* __restrict__ lcln_b,
                       const float* __restrict__ tw_w, const float* __restrict__ tw_b,
                       const float* __restrict__ twln_g, const float* __restrict__ twln_b,
                       const float* __restrict__ wdct, const float* __restrict__ wmax,
                       float* __restrict__ gate) {
  int n = blockIdx.x, c = threadIdx.x;
  __shared__ float xs[C_ + 2];
  __shared__ float att_s[C_];
  __shared__ float red[4];
  float g  = xg[n * C_ + c];
  float sv = wmax[c] * xmax[n * C_ + c] + wdct[c] * xdct[n * C_ + c];
  xs[c + 1] = sv;
  if (c == 0) { xs[0] = 0.f; xs[C_ + 1] = 0.f; }
  __syncthreads();
  float xl = lc_w[0] * xs[c] + lc_w[1] * xs[c + 1] + lc_w[2] * xs[c + 2] + lc_b[0];
  float t = g + sv + xl;
  float mu  = block_sum(t, red) * (1.f / C_);
  float dv  = t - mu;
  float var = block_sum(dv * dv, red) * (1.f / C_);
  float att = dv * rsqrtf(var + LN_EPS) * lcln_g[c] + lcln_b[c];
  att_s[c] = att;
  __syncthreads();
  float a2 = tw_b[c];
  const f4* wrow = (const f4*)(tw_w + c * C_);
  const f4* arow = (const f4*)att_s;
  #pragma unroll 8
  for (int k = 0; k < C_ / 4; ++k) a2 += dot4(wrow[k], arow[k]);
  float mu2  = block_sum(a2, red) * (1.f / C_);
  float d2   = a2 - mu2;
  float var2 = block_sum(d2 * d2, red) * (1.f / C_);
  float z = d2 * rsqrtf(var2 + LN_EPS) * twln_g[c] + twln_b[c];
  gate[n * C_ + c] = 1.f / (1.f + expf(-z));
}

// K5: out = x * gate[n,c], float4 grid-stride.
__global__ void k_scale(const float* __restrict__ x, const float* __restrict__ gate,
                        float* __restrict__ out) {
  const f4* x4 = (const f4*)x;
  f4* o4 = (f4*)out;
  const int total = N_ * C_ * Q_;
  for (int i = blockIdx.x * blockDim.x + threadIdx.x; i < total;
       i += gridDim.x * blockDim.x) {
    int nc = i / Q_;
    float gv = gate[nc];
    f4 v = x4[i];
    v *= gv;
    o4[i] = v;
  }
}

extern "C" void kernel_launch(void* const* d_in, const int* in_sizes, int n_in,
                              void* d_out, int out_size, void* d_ws, size_t ws_size,
                              hipStream_t stream) {
  const float* x      = (const float*)d_in[0];
  const float* gc_w   = (const float*)d_in[1];
  // d_in[2] = gc_b: softmax shift-invariant, unused
  const float* lc_w   = (const float*)d_in[3];
  const float* lc_b   = (const float*)d_in[4];
  const float* lcln_g = (const float*)d_in[5];
  const float* lcln_b = (const float*)d_in[6];
  const float* tw_w   = (const float*)d_in[7];
  const float* tw_b   = (const float*)d_in[8];
  const float* twln_g = (const float*)d_in[9];
  const float* twln_b = (const float*)d_in[10];
  const float* wdct   = (const float*)d_in[11];
  const float* wmax   = (const float*)d_in[12];
  float* out = (float*)d_out;

  float* ws    = (float*)d_ws;
  float* lpart = ws;                                   // NCH*N*S
  float* attn  = lpart + (size_t)NCH * N_ * S_;        // N*S
  float* xg    = attn + (size_t)N_ * S_;               // N*C
  float* xmax_ = xg + N_ * C_;
  float* xdct_ = xmax_ + N_ * C_;
  float* gate  = xdct_ + N_ * C_;

  hipLaunchKernelGGL(k_logits, dim3(NCH, N_, SQ), dim3(256), 0, stream, x, gc_w, lpart);
  hipLaunchKernelGGL(k_softmax, dim3(N_), dim3(256), 0, stream, lpart, attn);
  hipLaunchKernelGGL(k_stats, dim3(C_, N_), dim3(256), 0, stream, x, attn, xg, xmax_, xdct_);
  hipLaunchKernelGGL(k_gate, dim3(N_), dim3(256), 0, stream,
                     xg, xmax_, xdct_, lc_w, lc_b, lcln_g, lcln_b,
                     tw_w, tw_b, twln_g, twln_b, wdct, wmax, gate);
  hipLaunchKernelGGL(k_scale, dim3(2048), dim3(256), 0, stream, x, gate, out);
}

// Round 9
// 86.208 us; speedup vs baseline: 2.9625x; 1.0175x over previous
//
#include <hip/hip_runtime.h>
#include <math.h>

// Channelatt: x(32,256,56,56) f32 -> x * sigmoid(gate(n,c))
// Pipeline: k1 logits (x cold-ish read, 2048 blocks) -> k2 softmax ->
// k3 stats xg+max+dct (x warm read, 8192 blocks) -> k4 gate -> k5 scale (NT store).
// Budget hypothesis (R8): k1~20, k2~3, k3~15, k4~3, k5~30, gaps~15.

#define N_ 32
#define C_ 256
#define H_ 56
#define W_ 56
#define S_ 3136   // H_*W_
#define Q_ 784    // S_/4 (float4 units)
#define LN_EPS 1e-5f

#define NCH 16    // c-chunks in pass 1
#define CPC 16    // channels per chunk (NCH*CPC == C_)
#define SQ  4     // s-chunks in pass 1
#define QCH 196   // f4 per s-chunk (Q_/SQ)

using f4 = __attribute__((ext_vector_type(4))) float;

__device__ __forceinline__ float wave_sum(float v) {
  #pragma unroll
  for (int o = 32; o > 0; o >>= 1) v += __shfl_xor(v, o);
  return v;
}
__device__ __forceinline__ float wave_max(float v) {
  #pragma unroll
  for (int o = 32; o > 0; o >>= 1) v = fmaxf(v, __shfl_xor(v, o));
  return v;
}
__device__ __forceinline__ float block_sum(float v, float* red) {
  int lane = threadIdx.x & 63, wid = threadIdx.x >> 6;
  float w = wave_sum(v);
  __syncthreads();
  if (lane == 0) red[wid] = w;
  __syncthreads();
  return red[0] + red[1] + red[2] + red[3];
}
__device__ __forceinline__ float dot4(f4 a, f4 b) {
  return a.x * b.x + a.y * b.y + a.z * b.z + a.w * b.w;
}
__device__ __forceinline__ float max4(f4 a) {
  return fmaxf(fmaxf(a.x, a.y), fmaxf(a.z, a.w));
}

// K1: partial logits. Block = (c-chunk, n, s-chunk) = 16*32*4 = 2048 blocks.
__global__ __launch_bounds__(256)
void k_logits(const float* __restrict__ x, const float* __restrict__ gc_w,
              float* __restrict__ lpart) {
  int ch = blockIdx.x, n = blockIdx.y, sq = blockIdx.z;
  int tid = threadIdx.x;
  int c0 = ch * CPC;
  __shared__ float gw[CPC];
  if (tid < CPC) gw[tid] = gc_w[c0 + tid];
  __syncthreads();
  if (tid >= QCH) return;
  int q = sq * QCH + tid;
  const f4* xb = (const f4*)x + ((size_t)n * C_ + c0) * Q_ + q;
  f4 A = {0,0,0,0};
  #pragma unroll
  for (int c = 0; c < CPC; ++c) A += gw[c] * xb[(size_t)c * Q_];
  ((f4*)lpart)[((size_t)n * NCH + ch) * Q_ + q] = A;
}

// K2: fold 16 partials -> softmax over s per n. One block per n, float4.
__global__ void k_softmax(const float* __restrict__ lpart, float* __restrict__ attn) {
  int n = blockIdx.x, tid = threadIdx.x;
  __shared__ float red[4];
  const f4* lp = (const f4*)lpart + (size_t)n * NCH * Q_;
  f4 v[4];
  float m = -INFINITY;
  #pragma unroll
  for (int k = 0; k < 3; ++k) {
    int q = tid + k * 256;
    f4 acc = {0,0,0,0};
    #pragma unroll
    for (int ch = 0; ch < NCH; ++ch) acc += lp[(size_t)ch * Q_ + q];
    v[k] = acc;
    m = fmaxf(m, max4(acc));
  }
  if (tid < 16) {
    f4 acc = {0,0,0,0};
    #pragma unroll
    for (int ch = 0; ch < NCH; ++ch) acc += lp[(size_t)ch * Q_ + 768 + tid];
    v[3] = acc;
    m = fmaxf(m, max4(acc));
  } else {
    v[3] = f4{-INFINITY, -INFINITY, -INFINITY, -INFINITY};
  }
  float wm = wave_max(m);
  int lane = tid & 63, wid = tid >> 6;
  if (lane == 0) red[wid] = wm;
  __syncthreads();
  m = fmaxf(fmaxf(red[0], red[1]), fmaxf(red[2], red[3]));
  float z = 0.f;
  #pragma unroll
  for (int k = 0; k < 4; ++k) {
    v[k].x = expf(v[k].x - m); v[k].y = expf(v[k].y - m);
    v[k].z = expf(v[k].z - m); v[k].w = expf(v[k].w - m);
    z += v[k].x + v[k].y + v[k].z + v[k].w;   // exp(-inf)=0 for tail lanes
  }
  z = block_sum(z, red);
  float inv = 1.f / z;
  f4* ap = (f4*)attn + (size_t)n * Q_;
  #pragma unroll
  for (int k = 0; k < 3; ++k) ap[tid + k * 256] = v[k] * inv;
  if (tid < 16) ap[768 + tid] = v[3] * inv;
}

// K3: per (n,c): x_g, x_max, x_dct in one warm x pass. Block per (c,n) = 8192.
__global__ void k_stats(const float* __restrict__ x, const float* __restrict__ attn,
                        float* __restrict__ xg, float* __restrict__ xmax,
                        float* __restrict__ xdct) {
  int c = blockIdx.x, n = blockIdx.y, tid = threadIdx.x;
  __shared__ float bh[H_];
  __shared__ f4 bw4[14];
  __shared__ float red[3][4];
  int grp = c >> 6;
  int u = grp >> 1, vv = grp & 1;
  const float invs = 0.13363062f;   // 1/sqrt(56)
  const float sq2  = 1.41421356f;
  if (tid < H_) {
    float b = cosf((float)M_PI * u * (tid + 0.5f) / H_) * invs;
    bh[tid] = u ? b * sq2 : b;
  } else if (tid >= 64 && tid < 64 + 14) {
    int j = tid - 64;
    f4 b;
    #pragma unroll
    for (int e = 0; e < 4; ++e) {
      float t = cosf((float)M_PI * vv * (4 * j + e + 0.5f) / W_) * invs;
      ((float*)&b)[e] = vv ? t * sq2 : t;
    }
    bw4[j] = b;
  }
  __syncthreads();
  const f4* xp = (const f4*)(x + ((size_t)n * C_ + c) * S_);
  const f4* ap = (const f4*)(attn + (size_t)n * S_);
  float g = 0.f, d = 0.f, mx = -INFINITY;
  #pragma unroll
  for (int k = 0; k < 3; ++k) {
    int q = tid + k * 256;
    f4 xv = xp[q], av = ap[q];
    g += dot4(xv, av);
    mx = fmaxf(max4(xv), mx);
    int h = q / 14;
    d += bh[h] * dot4(xv, bw4[q - h * 14]);
  }
  if (tid < 16) {
    int q = 768 + tid;
    f4 xv = xp[q], av = ap[q];
    g += dot4(xv, av);
    mx = fmaxf(max4(xv), mx);
    int h = q / 14;
    d += bh[h] * dot4(xv, bw4[q - h * 14]);
  }
  float gs = wave_sum(g), ms = wave_max(mx), ds = wave_sum(d);
  int lane = tid & 63, wid = tid >> 6;
  if (lane == 0) { red[0][wid] = gs; red[1][wid] = ms; red[2][wid] = ds; }
  __syncthreads();
  if (tid == 0) {
    xg[n * C_ + c]   = red[0][0] + red[0][1] + red[0][2] + red[0][3];
    xmax[n * C_ + c] = fmaxf(fmaxf(red[1][0], red[1][1]), fmaxf(red[1][2], red[1][3]));
    xdct[n * C_ + c] = red[2][0] + red[2][1] + red[2][2] + red[2][3];
  }
}

// K4: per-(n,c) gate math. One block per n, thread = channel.
__global__ void k_gate(const float* __restrict__ xg, const float* __restrict__ xmax,
                       const float* __restrict__ xdct,
                       const float* __restrict__ lc_w, const float* __restrict__ lc_b,
                       const float* __restrict__ lcln_g, const float* __restrict__ lcln_b,
                       const float* __restrict__ tw_w, const float* __restrict__ tw_b,
                       const float* __restrict__ twln_g, const float* __restrict__ twln_b,
                       const float* __restrict__ wdct, const float* __restrict__ wmax,
                       float* __restrict__ gate) {
  int n = blockIdx.x, c = threadIdx.x;
  __shared__ float xs[C_ + 2];
  __shared__ float att_s[C_];
  __shared__ float red[4];
  float g  = xg[n * C_ + c];
  float sv = wmax[c] * xmax[n * C_ + c] + wdct[c] * xdct[n * C_ + c];
  xs[c + 1] = sv;
  if (c == 0) { xs[0] = 0.f; xs[C_ + 1] = 0.f; }
  __syncthreads();
  float xl = lc_w[0] * xs[c] + lc_w[1] * xs[c + 1] + lc_w[2] * xs[c + 2] + lc_b[0];
  float t = g + sv + xl;
  float mu  = block_sum(t, red) * (1.f / C_);
  float dv  = t - mu;
  float var = block_sum(dv * dv, red) * (1.f / C_);
  float att = dv * rsqrtf(var + LN_EPS) * lcln_g[c] + lcln_b[c];
  att_s[c] = att;
  __syncthreads();
  float a2 = tw_b[c];
  const f4* wrow = (const f4*)(tw_w + c * C_);
  const f4* arow = (const f4*)att_s;
  #pragma unroll 8
  for (int k = 0; k < C_ / 4; ++k) a2 += dot4(wrow[k], arow[k]);
  float mu2  = block_sum(a2, red) * (1.f / C_);
  float d2   = a2 - mu2;
  float var2 = block_sum(d2 * d2, red) * (1.f / C_);
  float z = d2 * rsqrtf(var2 + LN_EPS) * twln_g[c] + twln_b[c];
  gate[n * C_ + c] = 1.f / (1.f + expf(-z));
}

// K5: out = x * gate[n,c], float4 grid-stride, NONTEMPORAL stores:
// out is never re-read -> don't allocate 103 MB in L2/L3, keep x resident.
__global__ void k_scale(const float* __restrict__ x, const float* __restrict__ gate,
                        float* __restrict__ out) {
  const f4* x4 = (const f4*)x;
  f4* o4 = (f4*)out;
  const int total = N_ * C_ * Q_;
  for (int i = blockIdx.x * blockDim.x + threadIdx.x; i < total;
       i += gridDim.x * blockDim.x) {
    int nc = i / Q_;
    float gv = gate[nc];
    f4 v = x4[i];
    v *= gv;
    __builtin_nontemporal_store(v, &o4[i]);
  }
}

extern "C" void kernel_launch(void* const* d_in, const int* in_sizes, int n_in,
                              void* d_out, int out_size, void* d_ws, size_t ws_size,
                              hipStream_t stream) {
  const float* x      = (const float*)d_in[0];
  const float* gc_w   = (const float*)d_in[1];
  // d_in[2] = gc_b: softmax shift-invariant, unused
  const float* lc_w   = (const float*)d_in[3];
  const float* lc_b   = (const float*)d_in[4];
  const float* lcln_g = (const float*)d_in[5];
  const float* lcln_b = (const float*)d_in[6];
  const float* tw_w   = (const float*)d_in[7];
  const float* tw_b   = (const float*)d_in[8];
  const float* twln_g = (const float*)d_in[9];
  const float* twln_b = (const float*)d_in[10];
  const float* wdct   = (const float*)d_in[11];
  const float* wmax   = (const float*)d_in[12];
  float* out = (float*)d_out;

  float* ws    = (float*)d_ws;
  float* lpart = ws;                                   // NCH*N*S
  float* attn  = lpart + (size_t)NCH * N_ * S_;        // N*S
  float* xg    = attn + (size_t)N_ * S_;               // N*C
  float* xmax_ = xg + N_ * C_;
  float* xdct_ = xmax_ + N_ * C_;
  float* gate  = xdct_ + N_ * C_;

  hipLaunchKernelGGL(k_logits, dim3(NCH, N_, SQ), dim3(256), 0, stream, x, gc_w, lpart);
  hipLaunchKernelGGL(k_softmax, dim3(N_), dim3(256), 0, stream, lpart, attn);
  hipLaunchKernelGGL(k_stats, dim3(C_, N_), dim3(256), 0, stream, x, attn, xg, xmax_, xdct_);
  hipLaunchKernelGGL(k_gate, dim3(N_), dim3(256), 0, stream,
                     xg, xmax_, xdct_, lc_w, lc_b, lcln_g, lcln_b,
                     tw_w, tw_b, twln_g, twln_b, wdct, wmax, gate);
  hipLaunchKernelGGL(k_scale, dim3(2048), dim3(256), 0, stream, x, gate, out);
}